// Round 13
// baseline (385.987 us; speedup 1.0000x reference)
//
#include <hip/hip_runtime.h>
#include <hip/hip_bf16.h>

// LinearAttention (efficient attention): B=4 N=4096 D_MODEL=1024 H=16 DH=64
// Pipeline (5 launches, 0 memsets):
//   prep(cvt + wqkv->B2 + wout^T + zero ctx/ksum) -> gemm_qkv (A-in-LDS, B-in-regs)
//   -> post_qkv(context ++ q_softmax) -> w2 (writes B2 layout) -> gemm_out.
// GEMM redesign (r13): LDS was the bottleneck (24 b128/wave/tile = 2304 cyc/CU/tile
// vs 620 MFMA). B now loads global->reg from B2[kchunk][col][8] layout (coalesced,
// L2-resident weights); LDS holds A only (64KB dbuf). 1 barrier + 1 vmcnt(0)/tile.

typedef unsigned short u16t;
typedef __bf16 bf16x8 __attribute__((ext_vector_type(8)));
typedef float f32x4 __attribute__((ext_vector_type(4)));
typedef unsigned short ushort8 __attribute__((ext_vector_type(8)));

__device__ __forceinline__ u16t f2bf(float f) {
    union { float f; unsigned int u; } v; v.f = f;
    unsigned int r = v.u + 0x7fffu + ((v.u >> 16) & 1u);
    return (u16t)(r >> 16);
}
__device__ __forceinline__ float bf2f(u16t h) {
    union { unsigned int u; float f; } v; v.u = ((unsigned int)h) << 16;
    return v.f;
}

#define GLOAD_LDS16(gptr, lptr) \
    __builtin_amdgcn_global_load_lds((const __attribute__((address_space(1))) unsigned int*)(gptr), \
                                     (__attribute__((address_space(3))) unsigned int*)(lptr), 16, 0, 0)

// ---------------- prep: cvt x (0..2047) | wqkv->B2 (2048..5119) | wout^T (5120..6143)
//                  | zero ctxT+ksum (6144..6211). 256 threads. ----------------
__global__ __launch_bounds__(256) void prep_kernel(const float* __restrict__ x, u16t* __restrict__ xb,
                                                   const float* __restrict__ w_qkv, u16t* __restrict__ wqkvB2,
                                                   const float* __restrict__ w_out, u16t* __restrict__ woutT,
                                                   float* __restrict__ zbase) {
    int bid = blockIdx.x, t = threadIdx.x;
    if (bid < 2048) {
        int i = (bid * 256 + t) * 4;
        for (; i < 16777216; i += 2048 * 256 * 4) {
            float4 v = *(const float4*)(x + i);
            ushort4 o;
            o.x = f2bf(v.x); o.y = f2bf(v.y); o.z = f2bf(v.z); o.w = f2bf(v.w);
            *(ushort4*)(xb + i) = o;
        }
        return;
    }
    if (bid >= 6144) {
        // zero ctxT (1MB) + ksum (64KB) = 69632 float4
        float4* z = (float4*)zbase;
        int i = (bid - 6144) * 256 + t;
        for (; i < 69632; i += 68 * 256) z[i] = make_float4(0.f, 0.f, 0.f, 0.f);
        return;
    }
    if (bid < 5120) {
        // wqkv [1024 k][3072 n] f32 -> B2[(kc*3072 + n)*8 + j] bf16
        int b2 = bid - 2048;
        int k0 = (b2 / 96) * 32, n0 = (b2 % 96) * 32;
        __shared__ float tile[32][33];
        int tx = t & 31, ty = t >> 5;
        for (int i = 0; i < 32; i += 8)
            tile[ty + i][tx] = w_qkv[(size_t)(k0 + ty + i) * 3072 + n0 + tx];
        __syncthreads();
        if (ty < 4) {
            ushort8 o;
#pragma unroll
            for (int j = 0; j < 8; j++) o[j] = f2bf(tile[ty * 8 + j][tx]);
            *(ushort8*)(&wqkvB2[((size_t)((k0 >> 3) + ty) * 3072 + n0 + tx) * 8]) = o;
        }
        return;
    }
    {
        // wout [1024][1024] f32 -> woutT [c][r] bf16 (row-major transpose, for w2_kernel)
        int b3 = bid - 5120;
        int c0 = (b3 & 31) * 32, r0 = (b3 >> 5) * 32;
        __shared__ float tile[32][33];
        int tx = t & 31, ty = t >> 5;
        for (int i = 0; i < 32; i += 8)
            tile[ty + i][tx] = w_out[(size_t)(r0 + ty + i) * 1024 + c0 + tx];
        __syncthreads();
        for (int i = 0; i < 32; i += 8)
            woutT[(size_t)(c0 + ty + i) * 1024 + r0 + tx] = f2bf(tile[tx][ty + i]);
    }
}

// ---------------- 256x256 bf16 GEMM body (r13): C = A * B2^T, K=1024 ----------------
// A [M][lda] bf16 row-major staged to LDS (gload_lds, T2 swizzle, 64KB dbuf).
// B2 [(kc)*NC + col][8] bf16: fragments loaded global->reg (coalesced 256B runs).
// 512 threads = 8 waves (2Mx4N), per-wave 128x64, BK=64, 16 K-tiles.
// Per tile: issue B(kt+1)->regs + A-stage(kt+1) | 16 ds_read A frags | 64 MFMA |
// vmcnt(0) | barrier. Named bE/bO reg sets (no runtime vec indexing).
// BATCHB: B2 += (by>>4)<<20. KSUM: k-col blocks accumulate column sum(exp) -> ksum.
template<int OUTF32, int BIAS, int BATCHB, int KSUM, int NC>
__device__ __forceinline__ void gemm256_body(const u16t* __restrict__ A, const u16t* __restrict__ B2,
                                             void* __restrict__ Cout, const float* __restrict__ bias,
                                             float* __restrict__ ksum, int N, int NBX, int lda) {
    __shared__ __align__(16) u16t lds[32768];   // 64 KB: 2 x 16384 (A dbuf)
    const int t = threadIdx.x;
    const int l = t & 63, w = t >> 6;
    const int wm = w >> 2, wn = w & 3;

    int cpx = gridDim.x >> 3;
    int wg = ((int)blockIdx.x & 7) * cpx + ((int)blockIdx.x >> 3);
    int bx = wg % NBX, by = wg / NBX;
    const int m0 = by * 256, n0 = bx * 256;
    if (BATCHB) B2 += (size_t)(by >> 4) << 20;

    // A fragment read addressing (swizzle folded; verified conflict-free r3)
    const int colk0 = ((l >> 4) ^ (l & 7)) * 8;
    const int colk1 = colk0 ^ 32;
    const int abase = (wm * 32 + (l & 15)) * 64;

    // A staging
    const int rr = w * 8 + (l >> 3);
    const int coloff = ((l ^ (l >> 3)) & 7) * 8;
    const int rowA = rr + ((rr >= 32) ? 96 : 0);
    const u16t* pa_st = A + (size_t)(m0 + rowA) * lda + coloff;
    const int so = w * 512;

    // B fragment addressing
    const int bcol = n0 + wn * 64 + (l & 15);
    const int ccl = l >> 4;   // 0..3

#define ASTAGE(kto, pb) do { \
    size_t k64_ = (size_t)(kto) * 64; \
    GLOAD_LDS16(pa_st + k64_,                    &lds[(pb) * 16384 + so]); \
    GLOAD_LDS16(pa_st + k64_ + (size_t)32 * lda, &lds[(pb) * 16384 + 4096 + so]); \
    GLOAD_LDS16(pa_st + k64_ + (size_t)64 * lda, &lds[(pb) * 16384 + 8192 + so]); \
    GLOAD_LDS16(pa_st + k64_ + (size_t)96 * lda, &lds[(pb) * 16384 + 12288 + so]); \
} while (0)

#define BLOAD(kto, breg) do { \
    _Pragma("unroll") \
    for (int ni = 0; ni < 4; ++ni) \
        _Pragma("unroll") \
        for (int kk = 0; kk < 2; ++kk) \
            breg[ni][kk] = *(const bf16x8*)&B2[((size_t)((kto) * 8 + kk * 4 + ccl) * NC + bcol + ni * 16) * 8]; \
} while (0)

#define TILE_BODY(kt, p, bCur, bNxt) do { \
    if ((kt) + 1 < 16) { BLOAD((kt) + 1, bNxt); ASTAGE((kt) + 1, (p) ^ 1); } \
    const u16t* lA = &lds[(p) * 16384]; \
    bf16x8 af[4][2][2]; \
    _Pragma("unroll") \
    for (int g = 0; g < 4; ++g) { \
        af[g][0][0] = *(const bf16x8*)&lA[g * 4096 + abase + colk0]; \
        af[g][0][1] = *(const bf16x8*)&lA[g * 4096 + abase + colk1]; \
        af[g][1][0] = *(const bf16x8*)&lA[g * 4096 + abase + 1024 + colk0]; \
        af[g][1][1] = *(const bf16x8*)&lA[g * 4096 + abase + 1024 + colk1]; \
    } \
    __builtin_amdgcn_s_setprio(1); \
    _Pragma("unroll") \
    for (int g = 0; g < 4; ++g) \
        _Pragma("unroll") \
        for (int dm = 0; dm < 2; ++dm) \
            _Pragma("unroll") \
            for (int ni = 0; ni < 4; ++ni) \
                _Pragma("unroll") \
                for (int kk = 0; kk < 2; ++kk) \
                    acc[g * 2 + dm][ni] = __builtin_amdgcn_mfma_f32_16x16x32_bf16( \
                        af[g][dm][kk], bCur[ni][kk], acc[g * 2 + dm][ni], 0, 0, 0); \
    __builtin_amdgcn_s_setprio(0); \
    asm volatile("s_waitcnt vmcnt(0)" ::: "memory"); \
    __builtin_amdgcn_s_barrier(); \
} while (0)

    f32x4 acc[8][4] = {};
    bf16x8 bE[4][2], bO[4][2];

    // prologue: tile 0
    ASTAGE(0, 0);
    BLOAD(0, bE);
    asm volatile("s_waitcnt vmcnt(0)" ::: "memory");
    __builtin_amdgcn_s_barrier();

#pragma unroll
    for (int k2 = 0; k2 < 8; ++k2) {
        TILE_BODY(2 * k2,     0, bE, bO);
        TILE_BODY(2 * k2 + 1, 1, bO, bE);
    }
#undef TILE_BODY
#undef BLOAD
#undef ASTAGE

    // ---- KSUM epilogue: per-column sum of exp over this block's 256 rows ----
    if (KSUM && n0 >= 1024 && n0 < 2048) {
#pragma unroll
        for (int ni = 0; ni < 4; ++ni) {
            float se = 0.f;
#pragma unroll
            for (int mi = 0; mi < 8; ++mi)
#pragma unroll
                for (int j = 0; j < 4; ++j)
                    se += __expf(acc[mi][ni][j]);
            se += __shfl_xor(se, 16);
            se += __shfl_xor(se, 32);
            if ((l >> 4) == 0)
                atomicAdd(&ksum[(by >> 4) * 1024 + (n0 - 1024) + wn * 64 + ni * 16 + l], se);
        }
    }

#pragma unroll
    for (int mi = 0; mi < 8; ++mi) {
        int row = m0 + wm * 128 + mi * 16 + ((l >> 4) << 2);
#pragma unroll
        for (int ni = 0; ni < 4; ++ni) {
            int col = n0 + wn * 64 + ni * 16 + (l & 15);
            float bv = BIAS ? bias[col] : 0.f;
#pragma unroll
            for (int j = 0; j < 4; ++j) {
                float v = acc[mi][ni][j] + bv;
                if (OUTF32) ((float*)Cout)[(size_t)(row + j) * N + col] = v;
                else        ((u16t*)Cout)[(size_t)(row + j) * N + col] = f2bf(v);
            }
        }
    }
}

// GEMM1: [16384,1024] x [1024,3072] -> qkv bf16, + k column sum-exp
__global__ __launch_bounds__(512, 2) void gemm_qkv(const u16t* __restrict__ A, const u16t* __restrict__ B2,
                                                   u16t* __restrict__ C, float* __restrict__ ksum) {
    gemm256_body<0, 0, 0, 1, 3072>(A, B2, C, nullptr, ksum, 3072, 12, 1024);
}

// final: out[b] = qsm[b] (lda=3072, cols 0..1023) x W2[b] + bias, f32
__global__ __launch_bounds__(512, 2) void gemm_out(const u16t* __restrict__ A, const u16t* __restrict__ B2,
                                                   float* __restrict__ C, const float* __restrict__ bias) {
    gemm256_body<1, 1, 1, 0, 1024>(A, B2, C, bias, nullptr, 1024, 4, 3072);
}

// ---------------- post_qkv: context (blocks 0..511) ++ q_softmax (512..1535) ----------
__global__ __launch_bounds__(256) void post_qkv(u16t* __restrict__ qkv,
                                                const float* __restrict__ ksum,
                                                float* __restrict__ ctxT) {
    int bid = blockIdx.x, t = threadIdx.x;
    if (bid < 512) {
        int bh = bid >> 3, chunk = bid & 7;
        int b = bh >> 4, h = bh & 15;
        __shared__ u16t kT[64 * 136];
        __shared__ u16t vT[64 * 136];
        int lane = t & 63, w = t >> 6;
        f32x4 acc[4] = {};
        for (int sub = 0; sub < 4; sub++) {
            size_t rowbase = ((size_t)b * 4096 + chunk * 512 + sub * 128) * 3072 + h * 64;
#pragma unroll
            for (int i = 0; i < 4; i++) {
                int P = t + 256 * i;
                int n = P >> 3, c = P & 7;
                size_t ro = rowbase + (size_t)n * 3072 + c * 8;
                ushort8 k8 = *(const ushort8*)(&qkv[ro + 1024]);
                ushort8 v8 = *(const ushort8*)(&qkv[ro + 2048]);
                int nx = n ^ (c << 3);
#pragma unroll
                for (int j = 0; j < 8; j++) {
                    kT[(c * 8 + j) * 136 + nx] = f2bf(__expf(bf2f(k8[j])));
                    vT[(c * 8 + j) * 136 + nx] = v8[j];
                }
            }
            __syncthreads();
#pragma unroll
            for (int ks = 0; ks < 4; ks++) {
                int er = w * 16 + (lane & 15);
                int nb = ks * 32 + ((lane >> 4) << 3);
                bf16x8 a = *(const bf16x8*)(&vT[er * 136 + (nb ^ ((er >> 3) << 3))]);
#pragma unroll
                for (int ct = 0; ct < 4; ct++) {
                    int dr = ct * 16 + (lane & 15);
                    bf16x8 bb = *(const bf16x8*)(&kT[dr * 136 + (nb ^ ((dr >> 3) << 3))]);
                    acc[ct] = __builtin_amdgcn_mfma_f32_16x16x32_bf16(a, bb, acc[ct], 0, 0, 0);
                }
            }
            __syncthreads();
        }
#pragma unroll
        for (int ct = 0; ct < 4; ct++) {
            int e = w * 16 + ((lane >> 4) << 2);
            int dd = ct * 16 + (lane & 15);
            float gi = 1.0f / ksum[b * 1024 + h * 64 + dd];
#pragma unroll
            for (int j = 0; j < 4; j++)
                atomicAdd(&ctxT[(size_t)bh * 4096 + (e + j) * 64 + dd], acc[ct][j] * gi);
        }
        return;
    }
    // ---- q softmax rows ----
    int qb = bid - 512;
#pragma unroll
    for (int it = 0; it < 8; ++it) {
        int r = qb * 256 + it * 32 + (t >> 3);
        size_t addr = (size_t)(r >> 4) * 3072 + (r & 15) * 64 + (t & 7) * 8;
        ushort8 ch = *(const ushort8*)(&qkv[addr]);
        float v0 = bf2f(ch[0]), v1 = bf2f(ch[1]), v2 = bf2f(ch[2]), v3 = bf2f(ch[3]);
        float v4 = bf2f(ch[4]), v5 = bf2f(ch[5]), v6 = bf2f(ch[6]), v7 = bf2f(ch[7]);
        float m = fmaxf(fmaxf(fmaxf(v0, v1), fmaxf(v2, v3)), fmaxf(fmaxf(v4, v5), fmaxf(v6, v7)));
        m = fmaxf(m, __shfl_xor(m, 1)); m = fmaxf(m, __shfl_xor(m, 2)); m = fmaxf(m, __shfl_xor(m, 4));
        float e0 = __expf(v0 - m), e1 = __expf(v1 - m), e2 = __expf(v2 - m), e3 = __expf(v3 - m);
        float e4 = __expf(v4 - m), e5 = __expf(v5 - m), e6 = __expf(v6 - m), e7 = __expf(v7 - m);
        float s = e0 + e1 + e2 + e3 + e4 + e5 + e6 + e7;
        s += __shfl_xor(s, 1); s += __shfl_xor(s, 2); s += __shfl_xor(s, 4);
        float inv = 0.125f / s;
        ushort8 o;
        o[0] = f2bf(e0 * inv); o[1] = f2bf(e1 * inv); o[2] = f2bf(e2 * inv); o[3] = f2bf(e3 * inv);
        o[4] = f2bf(e4 * inv); o[5] = f2bf(e5 * inv); o[6] = f2bf(e6 * inv); o[7] = f2bf(e7 * inv);
        *(ushort8*)(&qkv[addr]) = o;
    }
}

// ---------------- W2: w2t in B2 layout: w2t[b][(hc*1024 + j)*8 + j8] ----------------
// W2[b][j][h*64+d] = sum_e ctxT[bh][e][d] * woutT[j][h*64+e]; hc = (h*64+d)/8.
__global__ __launch_bounds__(256) void w2_kernel(const float* __restrict__ ctxT,
                                                 const u16t* __restrict__ woutT,
                                                 u16t* __restrict__ w2t) {
    int bh = blockIdx.x, jc = blockIdx.y;
    int b = bh >> 4, h = bh & 15;
    __shared__ u16t cb[64][72];
    __shared__ u16t wl[256][72];
    int t = threadIdx.x;
#pragma unroll
    for (int i = 0; i < 16; i++) {
        int f = t + 256 * i;
        cb[f & 63][f >> 6] = f2bf(ctxT[(size_t)bh * 4096 + f]);
    }
#pragma unroll
    for (int i = 0; i < 8; i++) {
        int f = t + 256 * i;
        int r = f >> 3, q = f & 7;
        *(uint4*)(&wl[r][q * 8]) = *(const uint4*)(&woutT[(size_t)(jc * 256 + r) * 1024 + h * 64 + q * 8]);
    }
    __syncthreads();
    int l = t & 63, w = t >> 6;
    f32x4 acc[4][4] = {};
#pragma unroll
    for (int kk = 0; kk < 2; kk++) {
        bf16x8 af[4], bfr[4];
#pragma unroll
        for (int mt = 0; mt < 4; mt++)
            af[mt] = *(const bf16x8*)&wl[w * 64 + mt * 16 + (l & 15)][(l >> 4) * 8 + kk * 32];
#pragma unroll
        for (int nt = 0; nt < 4; nt++)
            bfr[nt] = *(const bf16x8*)&cb[nt * 16 + (l & 15)][(l >> 4) * 8 + kk * 32];
#pragma unroll
        for (int mt = 0; mt < 4; mt++)
#pragma unroll
            for (int nt = 0; nt < 4; nt++)
                acc[mt][nt] = __builtin_amdgcn_mfma_f32_16x16x32_bf16(af[mt], bfr[nt], acc[mt][nt], 0, 0, 0);
    }
    __syncthreads();
    // stage result to LDS (wl reused as [j][dd])
#pragma unroll
    for (int mt = 0; mt < 4; mt++) {
        int jl = w * 64 + mt * 16 + ((l >> 4) << 2);
#pragma unroll
        for (int nt = 0; nt < 4; nt++) {
            int dd = nt * 16 + (l & 15);
#pragma unroll
            for (int jj = 0; jj < 4; jj++)
                wl[jl + jj][dd] = f2bf(acc[mt][nt][jj]);
        }
    }
    __syncthreads();
    // coalesced B2-layout store: (j, cc) pairs
#pragma unroll
    for (int i = 0; i < 8; i++) {
        int idx = t + 256 * i;
        int j = idx & 255, cc = idx >> 8;   // cc 0..7
        ushort8 o = *(const ushort8*)(&wl[j][cc * 8]);
        *(ushort8*)(&w2t[((size_t)b << 20) + ((size_t)(h * 8 + cc) * 1024 + jc * 256 + j) * 8]) = o;
    }
}

// ---------------- launch ----------------

extern "C" void kernel_launch(void* const* d_in, const int* in_sizes, int n_in,
                              void* d_out, int out_size, void* d_ws, size_t ws_size,
                              hipStream_t stream) {
    const float* x     = (const float*)d_in[0];
    const float* w_qkv = (const float*)d_in[1];
    const float* w_out = (const float*)d_in[2];
    const float* b_out = (const float*)d_in[3];
    float* out = (float*)d_out;
    char* ws = (char*)d_ws;

    size_t o_xb    = 0;                       // 16384*1024*2 = 33554432 (reused as w2t)
    size_t o_wqkvT = 33554432;                // 3072*1024*2  = 6291456 (B2 layout)
    size_t o_woutT = 39845888;                // 1024*1024*2  = 2097152
    size_t o_qkv   = 41943040;                // 16384*3072*2 = 100663296
    size_t o_ctx   = 142606336;               // 64*64*64*4   = 1048576
    size_t o_ksum  = 143654912;               // 65536 (contiguous after ctx for zeroing)
    size_t needed  = 143720448;
    if (ws_size < needed) return;

    u16t* xb     = (u16t*)(ws + o_xb);
    u16t* w2t    = (u16t*)(ws + o_xb);        // reuse (xb dead after gemm_qkv)
    u16t* wqkvB2 = (u16t*)(ws + o_wqkvT);
    u16t* woutT  = (u16t*)(ws + o_woutT);
    u16t* qkvb   = (u16t*)(ws + o_qkv);
    float* ctxT  = (float*)(ws + o_ctx);
    float* ksum  = (float*)(ws + o_ksum);

    // cvt + wqkv->B2 + wout^T + zero(ctxT,ksum), one launch
    prep_kernel<<<6212, 256, 0, stream>>>(x, xb, w_qkv, wqkvB2, w_out, woutT, ctxT);

    // GEMM1: [16384,1024] x [1024,3072] -> qkv (raw), k col sum-exp -> ksum
    gemm_qkv<<<768, 512, 0, stream>>>(xb, wqkvB2, qkvb, ksum);

    // context (512 blocks) ++ q softmax (1024 blocks), one launch
    post_qkv<<<1536, 256, 0, stream>>>(qkvb, ksum, ctxT);

    // W2 in B2 layout
    w2_kernel<<<dim3(64, 4), 256, 0, stream>>>(ctxT, woutT, w2t);

    // out[b] = qsm[b] x W2[b] + bias (f32)
    gemm_out<<<256, 512, 0, stream>>>(qkvb, w2t, out, b_out);
}

// Round 14
// 201.810 us; speedup vs baseline: 1.9126x; 1.9126x over previous
//
#include <hip/hip_runtime.h>
#include <hip/hip_bf16.h>

// LinearAttention (efficient attention): B=4 N=4096 D_MODEL=1024 H=16 DH=64
// Pipeline (5 launches + 2 memsets):
//   prep(cvt + 2 transposes) -> gemm_qkv (256^2 barrier-lite, +k sum-exp epilogue)
//   -> post_qkv(context ++ q_softmax, fused launch) -> w2 -> gemm_out.
//   attn_gemm eliminated via (qsm*ctx)*w_out == qsm*(ctx*w_out).
//   k-softmax max-pass eliminated (|k| small -> exp safe).
// r13's B-in-regs redesign REVERTED (278us: vmcnt(0) drained B-prefetch every tile,
// 2x B demand missed L2). B-through-LDS (read once, broadcast) is correct here.

typedef unsigned short u16t;
typedef __bf16 bf16x8 __attribute__((ext_vector_type(8)));
typedef float f32x4 __attribute__((ext_vector_type(4)));
typedef unsigned short ushort8 __attribute__((ext_vector_type(8)));

__device__ __forceinline__ u16t f2bf(float f) {
    union { float f; unsigned int u; } v; v.f = f;
    unsigned int r = v.u + 0x7fffu + ((v.u >> 16) & 1u);
    return (u16t)(r >> 16);
}
__device__ __forceinline__ float bf2f(u16t h) {
    union { unsigned int u; float f; } v; v.u = ((unsigned int)h) << 16;
    return v.f;
}

#define GLOAD_LDS16(gptr, lptr) \
    __builtin_amdgcn_global_load_lds((const __attribute__((address_space(1))) unsigned int*)(gptr), \
                                     (__attribute__((address_space(3))) unsigned int*)(lptr), 16, 0, 0)
#define SFENCE asm volatile("" ::: "memory")

// ---------------- prep: cvt x->bf16 (blocks 0..2047) | transpose wqkv (2048..5119)
//                  | transpose wout (5120..6143). 256 threads. ----------------
__global__ __launch_bounds__(256) void prep_kernel(const float* __restrict__ x, u16t* __restrict__ xb,
                                                   const float* __restrict__ w_qkv, u16t* __restrict__ wqkvT,
                                                   const float* __restrict__ w_out, u16t* __restrict__ woutT) {
    int bid = blockIdx.x, t = threadIdx.x;
    if (bid < 2048) {
        int i = (bid * 256 + t) * 4;
        for (; i < 16777216; i += 2048 * 256 * 4) {
            float4 v = *(const float4*)(x + i);
            ushort4 o;
            o.x = f2bf(v.x); o.y = f2bf(v.y); o.z = f2bf(v.z); o.w = f2bf(v.w);
            *(ushort4*)(xb + i) = o;
        }
        return;
    }
    __shared__ float tile[32][33];
    const float* in; u16t* out; int R, C, bx, by;
    if (bid < 5120) { in = w_qkv; out = wqkvT; R = 1024; C = 3072; int b2 = bid - 2048; bx = b2 % 96; by = b2 / 96; }
    else            { in = w_out; out = woutT; R = 1024; C = 1024; int b3 = bid - 5120; bx = b3 & 31; by = b3 >> 5; }
    int c0 = bx * 32, r0 = by * 32;
    int tx = t & 31, ty = t >> 5;
    for (int i = 0; i < 32; i += 8)
        tile[ty + i][tx] = in[(size_t)(r0 + ty + i) * C + c0 + tx];
    __syncthreads();
    for (int i = 0; i < 32; i += 8)
        out[(size_t)(c0 + ty + i) * R + r0 + tx] = f2bf(tile[tx][ty + i]);
}

// ---------------- 256x256 barrier-lite bf16 GEMM body (r6): C = A * Bt^T ----------------
// A [M][lda] bf16 row-major (cols 0..K-1), Bt [N][K] bf16 row-major. 512 threads = 8 waves
// (2Mx4N), per-wave 128x64, BK=64, LDS 128KB dbuf. T2 swizzle (conflict-free, r3-verified),
// XCD-bijective grid swizzle, 2 barriers/K-tile, counted vmcnt, no lgkm pins.
// BATCHB: Bt += (by>>4)<<20. KSUM: k-col blocks accumulate per-column sum(exp) -> ksum.
template<int OUTF32, int BIAS, int BATCHB, int KSUM>
__device__ __forceinline__ void gemm256_body(const u16t* __restrict__ A, const u16t* __restrict__ Bt,
                                             void* __restrict__ Cout, const float* __restrict__ bias,
                                             float* __restrict__ ksum,
                                             int M, int N, int K, int NBX, int lda) {
    __shared__ __align__(16) u16t lds[65536];   // 128 KB
    const int t = threadIdx.x;
    const int l = t & 63, w = t >> 6;
    const int wm = w >> 2, wn = w & 3;

    int cpx = gridDim.x >> 3;
    int wg = ((int)blockIdx.x & 7) * cpx + ((int)blockIdx.x >> 3);
    int bx = wg % NBX, by = wg / NBX;
    const int m0 = by * 256, n0 = bx * 256;
    const int NT = K >> 6;
    if (BATCHB) Bt += (size_t)(by >> 4) << 20;

    const int colk0 = ((l >> 4) ^ (l & 7)) * 8;
    const int colk1 = colk0 ^ 32;
    const int abase = (wm * 32 + (l & 15)) * 64;
    const int bbase = 16384 + (wn >> 1) * 8192 + ((wn & 1) * 64 + (l & 15)) * 64;

    const int rr = w * 8 + (l >> 3);
    const int coloff = ((l ^ (l >> 3)) & 7) * 8;
    const int rowA = rr + ((rr >= 32) ? 96 : 0);
    const u16t* pa_st = A  + (size_t)(m0 + rowA) * lda + coloff;
    const u16t* pb_st = Bt + (size_t)(n0 + rr) * K + coloff;
    const int so = w * 512;

#define SPAIR(qq, kto, pb) do { \
    size_t k64_ = (size_t)(kto) * 64; \
    if ((qq) == 0) { \
        GLOAD_LDS16(pb_st + k64_,                  &lds[(pb) * 32768 + 16384 + so]); \
        GLOAD_LDS16(pb_st + k64_ + (size_t)64 * K, &lds[(pb) * 32768 + 20480 + so]); \
    } else if ((qq) == 1) { \
        GLOAD_LDS16(pb_st + k64_ + (size_t)128 * K, &lds[(pb) * 32768 + 24576 + so]); \
        GLOAD_LDS16(pb_st + k64_ + (size_t)192 * K, &lds[(pb) * 32768 + 28672 + so]); \
    } else if ((qq) == 2) { \
        GLOAD_LDS16(pa_st + k64_,                    &lds[(pb) * 32768 + so]); \
        GLOAD_LDS16(pa_st + k64_ + (size_t)32 * lda, &lds[(pb) * 32768 + 4096 + so]); \
    } else { \
        GLOAD_LDS16(pa_st + k64_ + (size_t)64 * lda, &lds[(pb) * 32768 + 8192 + so]); \
        GLOAD_LDS16(pa_st + k64_ + (size_t)96 * lda, &lds[(pb) * 32768 + 12288 + so]); \
    } \
} while (0)

    f32x4 acc[8][4] = {};

    SPAIR(0, 0, 0); SPAIR(1, 0, 0); SPAIR(2, 0, 0);
    SFENCE;
    SPAIR(3, 0, 0);

    for (int kt = 0; kt < NT; ++kt) {
        const int p = kt & 1;
        const bool sn = (kt + 1 < NT);
        const u16t* lA = &lds[p * 32768];

        asm volatile("s_waitcnt vmcnt(2)" ::: "memory");
        __builtin_amdgcn_s_barrier();

        bf16x8 bfr[4][2];
#pragma unroll
        for (int ni = 0; ni < 4; ++ni) {
            bfr[ni][0] = *(const bf16x8*)&lA[bbase + ni * 1024 + colk0];
            bfr[ni][1] = *(const bf16x8*)&lA[bbase + ni * 1024 + colk1];
        }
        bf16x8 af1[2][2][2];
#pragma unroll
        for (int g = 0; g < 2; ++g) {
            af1[g][0][0] = *(const bf16x8*)&lA[g * 4096 + abase + colk0];
            af1[g][0][1] = *(const bf16x8*)&lA[g * 4096 + abase + colk1];
            af1[g][1][0] = *(const bf16x8*)&lA[g * 4096 + abase + 1024 + colk0];
            af1[g][1][1] = *(const bf16x8*)&lA[g * 4096 + abase + 1024 + colk1];
        }
        if (sn) { SPAIR(0, kt + 1, p ^ 1); SPAIR(1, kt + 1, p ^ 1); SPAIR(2, kt + 1, p ^ 1); }
        __builtin_amdgcn_s_setprio(1);
#pragma unroll
        for (int g = 0; g < 2; ++g)
#pragma unroll
            for (int dm = 0; dm < 2; ++dm)
#pragma unroll
                for (int ni = 0; ni < 4; ++ni)
#pragma unroll
                    for (int kk = 0; kk < 2; ++kk)
                        acc[g * 2 + dm][ni] = __builtin_amdgcn_mfma_f32_16x16x32_bf16(
                            af1[g][dm][kk], bfr[ni][kk], acc[g * 2 + dm][ni], 0, 0, 0);
        __builtin_amdgcn_s_setprio(0);

        if (sn) asm volatile("s_waitcnt vmcnt(6)" ::: "memory");
        else    asm volatile("s_waitcnt vmcnt(0)" ::: "memory");
        __builtin_amdgcn_s_barrier();

        bf16x8 af2[2][2][2];
#pragma unroll
        for (int g = 0; g < 2; ++g) {
            af2[g][0][0] = *(const bf16x8*)&lA[(g + 2) * 4096 + abase + colk0];
            af2[g][0][1] = *(const bf16x8*)&lA[(g + 2) * 4096 + abase + colk1];
            af2[g][1][0] = *(const bf16x8*)&lA[(g + 2) * 4096 + abase + 1024 + colk0];
            af2[g][1][1] = *(const bf16x8*)&lA[(g + 2) * 4096 + abase + 1024 + colk1];
        }
        if (sn) SPAIR(3, kt + 1, p ^ 1);
        __builtin_amdgcn_s_setprio(1);
#pragma unroll
        for (int g = 0; g < 2; ++g)
#pragma unroll
            for (int dm = 0; dm < 2; ++dm)
#pragma unroll
                for (int ni = 0; ni < 4; ++ni)
#pragma unroll
                    for (int kk = 0; kk < 2; ++kk)
                        acc[4 + g * 2 + dm][ni] = __builtin_amdgcn_mfma_f32_16x16x32_bf16(
                            af2[g][dm][kk], bfr[ni][kk], acc[4 + g * 2 + dm][ni], 0, 0, 0);
        __builtin_amdgcn_s_setprio(0);
    }
#undef SPAIR

    // ---- KSUM epilogue: per-column sum of exp over this block's 256 rows ----
    if (KSUM && n0 >= 1024 && n0 < 2048) {
#pragma unroll
        for (int ni = 0; ni < 4; ++ni) {
            float se = 0.f;
#pragma unroll
            for (int mi = 0; mi < 8; ++mi)
#pragma unroll
                for (int j = 0; j < 4; ++j)
                    se += __expf(acc[mi][ni][j]);
            se += __shfl_xor(se, 16);
            se += __shfl_xor(se, 32);
            if ((l >> 4) == 0)
                atomicAdd(&ksum[(by >> 4) * 1024 + (n0 - 1024) + wn * 64 + ni * 16 + l], se);
        }
    }

#pragma unroll
    for (int mi = 0; mi < 8; ++mi) {
        int row = m0 + wm * 128 + mi * 16 + ((l >> 4) << 2);
#pragma unroll
        for (int ni = 0; ni < 4; ++ni) {
            int col = n0 + wn * 64 + ni * 16 + (l & 15);
            float bv = BIAS ? bias[col] : 0.f;
#pragma unroll
            for (int j = 0; j < 4; ++j) {
                float v = acc[mi][ni][j] + bv;
                if (OUTF32) ((float*)Cout)[(size_t)(row + j) * N + col] = v;
                else        ((u16t*)Cout)[(size_t)(row + j) * N + col] = f2bf(v);
            }
        }
    }
}

// GEMM1: [16384,1024] x [1024,3072] -> qkv bf16, + k column sum-exp
__global__ __launch_bounds__(512, 2) void gemm_qkv(const u16t* __restrict__ A, const u16t* __restrict__ Bt,
                                                   u16t* __restrict__ C, float* __restrict__ ksum) {
    gemm256_body<0, 0, 0, 1>(A, Bt, C, nullptr, ksum, 16384, 3072, 1024, 12, 1024);
}

// final: out[b] = qsm[b] (lda=3072, cols 0..1023) x W2T[b]^T + bias, f32
__global__ __launch_bounds__(512, 2) void gemm_out(const u16t* __restrict__ A, const u16t* __restrict__ Bt,
                                                   float* __restrict__ C, const float* __restrict__ bias) {
    gemm256_body<1, 1, 1, 0>(A, Bt, C, bias, nullptr, 16384, 1024, 1024, 4, 3072);
}

// ---------------- post_qkv: context (blocks 0..511) ++ q_softmax (512..1535) ----------
// Independent work: ctx reads k/v thirds + ksum; qsm rewrites q third in place.
// ctx: ctxT[bh][e][d] = (sum_n v[n][e]*exp(k[n][d])) / ksum[d]; LDS XOR-swizzled
// transpose staging (ushort8 loads); unnormalized exp(k) (|k| small); 1/ksum at atomic.
// qsm: in-place softmax over d=64 per row-head, * SCALE, 8-lane groups.
__global__ __launch_bounds__(256) void post_qkv(u16t* __restrict__ qkv,
                                                const float* __restrict__ ksum,
                                                float* __restrict__ ctxT) {
    int bid = blockIdx.x, t = threadIdx.x;
    if (bid < 512) {
        int bh = bid >> 3, chunk = bid & 7;
        int b = bh >> 4, h = bh & 15;
        __shared__ u16t kT[64 * 136];
        __shared__ u16t vT[64 * 136];
        int lane = t & 63, w = t >> 6;
        f32x4 acc[4] = {};
        for (int sub = 0; sub < 4; sub++) {
            size_t rowbase = ((size_t)b * 4096 + chunk * 512 + sub * 128) * 3072 + h * 64;
#pragma unroll
            for (int i = 0; i < 4; i++) {
                int P = t + 256 * i;          // (n, d-chunk) pair
                int n = P >> 3, c = P & 7;
                size_t ro = rowbase + (size_t)n * 3072 + c * 8;
                ushort8 k8 = *(const ushort8*)(&qkv[ro + 1024]);
                ushort8 v8 = *(const ushort8*)(&qkv[ro + 2048]);
                int nx = n ^ (c << 3);
#pragma unroll
                for (int j = 0; j < 8; j++) {
                    kT[(c * 8 + j) * 136 + nx] = f2bf(__expf(bf2f(k8[j])));
                    vT[(c * 8 + j) * 136 + nx] = v8[j];
                }
            }
            __syncthreads();
#pragma unroll
            for (int ks = 0; ks < 4; ks++) {
                int er = w * 16 + (lane & 15);
                int nb = ks * 32 + ((lane >> 4) << 3);
                bf16x8 a = *(const bf16x8*)(&vT[er * 136 + (nb ^ ((er >> 3) << 3))]);
#pragma unroll
                for (int ct = 0; ct < 4; ct++) {
                    int dr = ct * 16 + (lane & 15);
                    bf16x8 bb = *(const bf16x8*)(&kT[dr * 136 + (nb ^ ((dr >> 3) << 3))]);
                    acc[ct] = __builtin_amdgcn_mfma_f32_16x16x32_bf16(a, bb, acc[ct], 0, 0, 0);
                }
            }
            __syncthreads();
        }
#pragma unroll
        for (int ct = 0; ct < 4; ct++) {
            int e = w * 16 + ((lane >> 4) << 2);
            int dd = ct * 16 + (lane & 15);
            float gi = 1.0f / ksum[b * 1024 + h * 64 + dd];
#pragma unroll
            for (int j = 0; j < 4; j++)
                atomicAdd(&ctxT[(size_t)bh * 4096 + (e + j) * 64 + dd], acc[ct][j] * gi);
        }
        return;
    }
    // ---- q softmax rows ----
    int qb = bid - 512;
#pragma unroll
    for (int it = 0; it < 8; ++it) {
        int r = qb * 256 + it * 32 + (t >> 3);
        size_t addr = (size_t)(r >> 4) * 3072 + (r & 15) * 64 + (t & 7) * 8;
        ushort8 ch = *(const ushort8*)(&qkv[addr]);
        float v0 = bf2f(ch[0]), v1 = bf2f(ch[1]), v2 = bf2f(ch[2]), v3 = bf2f(ch[3]);
        float v4 = bf2f(ch[4]), v5 = bf2f(ch[5]), v6 = bf2f(ch[6]), v7 = bf2f(ch[7]);
        float m = fmaxf(fmaxf(fmaxf(v0, v1), fmaxf(v2, v3)), fmaxf(fmaxf(v4, v5), fmaxf(v6, v7)));
        m = fmaxf(m, __shfl_xor(m, 1)); m = fmaxf(m, __shfl_xor(m, 2)); m = fmaxf(m, __shfl_xor(m, 4));
        float e0 = __expf(v0 - m), e1 = __expf(v1 - m), e2 = __expf(v2 - m), e3 = __expf(v3 - m);
        float e4 = __expf(v4 - m), e5 = __expf(v5 - m), e6 = __expf(v6 - m), e7 = __expf(v7 - m);
        float s = e0 + e1 + e2 + e3 + e4 + e5 + e6 + e7;
        s += __shfl_xor(s, 1); s += __shfl_xor(s, 2); s += __shfl_xor(s, 4);
        float inv = 0.125f / s;
        ushort8 o;
        o[0] = f2bf(e0 * inv); o[1] = f2bf(e1 * inv); o[2] = f2bf(e2 * inv); o[3] = f2bf(e3 * inv);
        o[4] = f2bf(e4 * inv); o[5] = f2bf(e5 * inv); o[6] = f2bf(e6 * inv); o[7] = f2bf(e7 * inv);
        *(ushort8*)(&qkv[addr]) = o;
    }
}

// ---------------- W2: W2T[b][j][h*64+d] = sum_e ctxT[bh][e][d] * woutT[j][h*64+e] ----
__global__ __launch_bounds__(256) void w2_kernel(const float* __restrict__ ctxT,
                                                 const u16t* __restrict__ woutT,
                                                 u16t* __restrict__ w2t) {
    int bh = blockIdx.x, jc = blockIdx.y;
    int b = bh >> 4, h = bh & 15;
    __shared__ u16t cb[64][72];
    __shared__ u16t wl[256][72];
    int t = threadIdx.x;
#pragma unroll
    for (int i = 0; i < 16; i++) {
        int f = t + 256 * i;
        cb[f & 63][f >> 6] = f2bf(ctxT[(size_t)bh * 4096 + f]);
    }
#pragma unroll
    for (int i = 0; i < 8; i++) {
        int f = t + 256 * i;
        int r = f >> 3, q = f & 7;
        *(uint4*)(&wl[r][q * 8]) = *(const uint4*)(&woutT[(size_t)(jc * 256 + r) * 1024 + h * 64 + q * 8]);
    }
    __syncthreads();
    int l = t & 63, w = t >> 6;
    f32x4 acc[4][4] = {};
#pragma unroll
    for (int kk = 0; kk < 2; kk++) {
        bf16x8 af[4], bfr[4];
#pragma unroll
        for (int mt = 0; mt < 4; mt++)
            af[mt] = *(const bf16x8*)&wl[w * 64 + mt * 16 + (l & 15)][(l >> 4) * 8 + kk * 32];
#pragma unroll
        for (int nt = 0; nt < 4; nt++)
            bfr[nt] = *(const bf16x8*)&cb[nt * 16 + (l & 15)][(l >> 4) * 8 + kk * 32];
#pragma unroll
        for (int mt = 0; mt < 4; mt++)
#pragma unroll
            for (int nt = 0; nt < 4; nt++)
                acc[mt][nt] = __builtin_amdgcn_mfma_f32_16x16x32_bf16(af[mt], bfr[nt], acc[mt][nt], 0, 0, 0);
    }
#pragma unroll
    for (int mt = 0; mt < 4; mt++) {
        int j = jc * 256 + w * 64 + mt * 16 + ((l >> 4) << 2);
#pragma unroll
        for (int nt = 0; nt < 4; nt++) {
            int dd = nt * 16 + (l & 15);
#pragma unroll
            for (int jj = 0; jj < 4; jj++)
                w2t[((size_t)b << 20) + (size_t)(j + jj) * 1024 + h * 64 + dd] = f2bf(acc[mt][nt][jj]);
        }
    }
}

// ---------------- launch ----------------

extern "C" void kernel_launch(void* const* d_in, const int* in_sizes, int n_in,
                              void* d_out, int out_size, void* d_ws, size_t ws_size,
                              hipStream_t stream) {
    const float* x     = (const float*)d_in[0];
    const float* w_qkv = (const float*)d_in[1];
    const float* w_out = (const float*)d_in[2];
    const float* b_out = (const float*)d_in[3];
    float* out = (float*)d_out;
    char* ws = (char*)d_ws;

    size_t o_xb    = 0;                       // 16384*1024*2 = 33554432 (reused as w2t)
    size_t o_wqkvT = 33554432;                // 3072*1024*2  = 6291456
    size_t o_woutT = 39845888;                // 1024*1024*2  = 2097152
    size_t o_qkv   = 41943040;                // 16384*3072*2 = 100663296
    size_t o_ctx   = 142606336;               // 64*64*64*4   = 1048576
    size_t o_ksum  = 143654912;               // 65536 reserved
    size_t needed  = 143720448;
    if (ws_size < needed) return;

    u16t* xb     = (u16t*)(ws + o_xb);
    u16t* w2t    = (u16t*)(ws + o_xb);        // reuse (xb dead after gemm_qkv)
    u16t* wqkvT  = (u16t*)(ws + o_wqkvT);
    u16t* woutT  = (u16t*)(ws + o_woutT);
    u16t* qkvb   = (u16t*)(ws + o_qkv);
    float* ctxT  = (float*)(ws + o_ctx);
    float* ksum  = (float*)(ws + o_ksum);

    hipMemsetAsync(ksum, 0, 65536, stream);
    hipMemsetAsync(ctxT, 0, 64 * 64 * 64 * 4, stream);

    // cvt + both weight transposes, one launch
    prep_kernel<<<6144, 256, 0, stream>>>(x, xb, w_qkv, wqkvT, w_out, woutT);

    // GEMM1: [16384,1024] x [1024,3072] -> qkv (raw), k col sum-exp -> ksum
    gemm_qkv<<<768, 512, 0, stream>>>(xb, wqkvT, qkvb, ksum);

    // context (512 blocks) ++ q softmax (1024 blocks), one launch
    post_qkv<<<1536, 256, 0, stream>>>(qkvb, ksum, ctxT);

    // W2T[b][j][hd] = sum_e ctx[bh][e][d] * w_out[he][j]
    w2_kernel<<<dim3(64, 4), 256, 0, stream>>>(ctxT, woutT, w2t);

    // out[b] = qsm[b] x W2T[b]^T + bias (f32)
    gemm_out<<<256, 512, 0, stream>>>(qkvb, w2t, out, b_out);
}

// Round 15
// 193.783 us; speedup vs baseline: 1.9918x; 1.0414x over previous
//
#include <hip/hip_runtime.h>
#include <hip/hip_bf16.h>

// LinearAttention (efficient attention): B=4 N=4096 D_MODEL=1024 H=16 DH=64
// Pipeline (5 launches, 0 memsets):
//   prep(cvt + 2 transposes + zero ctx/ksum) -> gemm_qkv (256^2 barrier-lite,
//   k-epilogue stores bf16(exp(k)) + column sum-exp) -> post_qkv(context ++ q_softmax)
//   -> w2 -> gemm_out.
//   attn_gemm eliminated via (qsm*ctx)*w_out == qsm*(ctx*w_out).
//   k-softmax max-pass eliminated (|k| <= ~6 -> exp f32/bf16-safe).
//   exp(k) computed ONCE in gemm_qkv epilogue (from f32 acc - more accurate than
//   re-exp of bf16 k); ctx stages it directly.

typedef unsigned short u16t;
typedef __bf16 bf16x8 __attribute__((ext_vector_type(8)));
typedef float f32x4 __attribute__((ext_vector_type(4)));
typedef unsigned short ushort8 __attribute__((ext_vector_type(8)));

__device__ __forceinline__ u16t f2bf(float f) {
    union { float f; unsigned int u; } v; v.f = f;
    unsigned int r = v.u + 0x7fffu + ((v.u >> 16) & 1u);
    return (u16t)(r >> 16);
}
__device__ __forceinline__ float bf2f(u16t h) {
    union { unsigned int u; float f; } v; v.u = ((unsigned int)h) << 16;
    return v.f;
}

#define GLOAD_LDS16(gptr, lptr) \
    __builtin_amdgcn_global_load_lds((const __attribute__((address_space(1))) unsigned int*)(gptr), \
                                     (__attribute__((address_space(3))) unsigned int*)(lptr), 16, 0, 0)
#define SFENCE asm volatile("" ::: "memory")

// ---------------- prep: cvt x->bf16 (0..2047) | transpose wqkv (2048..5119)
//                  | transpose wout (5120..6143) | zero ctxT+ksum (6144..6211) --------
__global__ __launch_bounds__(256) void prep_kernel(const float* __restrict__ x, u16t* __restrict__ xb,
                                                   const float* __restrict__ w_qkv, u16t* __restrict__ wqkvT,
                                                   const float* __restrict__ w_out, u16t* __restrict__ woutT,
                                                   float* __restrict__ zbase) {
    int bid = blockIdx.x, t = threadIdx.x;
    if (bid < 2048) {
        int i = (bid * 256 + t) * 4;
        for (; i < 16777216; i += 2048 * 256 * 4) {
            float4 v = *(const float4*)(x + i);
            ushort4 o;
            o.x = f2bf(v.x); o.y = f2bf(v.y); o.z = f2bf(v.z); o.w = f2bf(v.w);
            *(ushort4*)(xb + i) = o;
        }
        return;
    }
    if (bid >= 6144) {
        // zero ctxT (1MB) + ksum (64KB) = 69632 float4 (contiguous)
        float4* z = (float4*)zbase;
        int i = (bid - 6144) * 256 + t;
        for (; i < 69632; i += 68 * 256) z[i] = make_float4(0.f, 0.f, 0.f, 0.f);
        return;
    }
    __shared__ float tile[32][33];
    const float* in; u16t* out; int R, C, bx, by;
    if (bid < 5120) { in = w_qkv; out = wqkvT; R = 1024; C = 3072; int b2 = bid - 2048; bx = b2 % 96; by = b2 / 96; }
    else            { in = w_out; out = woutT; R = 1024; C = 1024; int b3 = bid - 5120; bx = b3 & 31; by = b3 >> 5; }
    int c0 = bx * 32, r0 = by * 32;
    int tx = t & 31, ty = t >> 5;
    for (int i = 0; i < 32; i += 8)
        tile[ty + i][tx] = in[(size_t)(r0 + ty + i) * C + c0 + tx];
    __syncthreads();
    for (int i = 0; i < 32; i += 8)
        out[(size_t)(c0 + ty + i) * R + r0 + tx] = f2bf(tile[tx][ty + i]);
}

// ---------------- 256x256 barrier-lite bf16 GEMM body (r6): C = A * Bt^T ----------------
// A [M][lda] bf16 row-major (cols 0..K-1), Bt [N][K] bf16 row-major. 512 threads = 8 waves
// (2Mx4N), per-wave 128x64, BK=64, LDS 128KB dbuf. T2 swizzle (conflict-free, r3-verified),
// XCD-bijective grid swizzle, 2 barriers/K-tile, counted vmcnt, no lgkm pins.
// BATCHB: Bt += (by>>4)<<20. KSUM: k-col blocks (n0 in [1024,2048)) run a fused
// epilogue: store bf16(exp(acc)) AND accumulate per-column sum(exp) -> ksum.
template<int OUTF32, int BIAS, int BATCHB, int KSUM>
__device__ __forceinline__ void gemm256_body(const u16t* __restrict__ A, const u16t* __restrict__ Bt,
                                             void* __restrict__ Cout, const float* __restrict__ bias,
                                             float* __restrict__ ksum,
                                             int M, int N, int K, int NBX, int lda) {
    __shared__ __align__(16) u16t lds[65536];   // 128 KB
    const int t = threadIdx.x;
    const int l = t & 63, w = t >> 6;
    const int wm = w >> 2, wn = w & 3;

    int cpx = gridDim.x >> 3;
    int wg = ((int)blockIdx.x & 7) * cpx + ((int)blockIdx.x >> 3);
    int bx = wg % NBX, by = wg / NBX;
    const int m0 = by * 256, n0 = bx * 256;
    const int NT = K >> 6;
    if (BATCHB) Bt += (size_t)(by >> 4) << 20;

    const int colk0 = ((l >> 4) ^ (l & 7)) * 8;
    const int colk1 = colk0 ^ 32;
    const int abase = (wm * 32 + (l & 15)) * 64;
    const int bbase = 16384 + (wn >> 1) * 8192 + ((wn & 1) * 64 + (l & 15)) * 64;

    const int rr = w * 8 + (l >> 3);
    const int coloff = ((l ^ (l >> 3)) & 7) * 8;
    const int rowA = rr + ((rr >= 32) ? 96 : 0);
    const u16t* pa_st = A  + (size_t)(m0 + rowA) * lda + coloff;
    const u16t* pb_st = Bt + (size_t)(n0 + rr) * K + coloff;
    const int so = w * 512;

#define SPAIR(qq, kto, pb) do { \
    size_t k64_ = (size_t)(kto) * 64; \
    if ((qq) == 0) { \
        GLOAD_LDS16(pb_st + k64_,                  &lds[(pb) * 32768 + 16384 + so]); \
        GLOAD_LDS16(pb_st + k64_ + (size_t)64 * K, &lds[(pb) * 32768 + 20480 + so]); \
    } else if ((qq) == 1) { \
        GLOAD_LDS16(pb_st + k64_ + (size_t)128 * K, &lds[(pb) * 32768 + 24576 + so]); \
        GLOAD_LDS16(pb_st + k64_ + (size_t)192 * K, &lds[(pb) * 32768 + 28672 + so]); \
    } else if ((qq) == 2) { \
        GLOAD_LDS16(pa_st + k64_,                    &lds[(pb) * 32768 + so]); \
        GLOAD_LDS16(pa_st + k64_ + (size_t)32 * lda, &lds[(pb) * 32768 + 4096 + so]); \
    } else { \
        GLOAD_LDS16(pa_st + k64_ + (size_t)64 * lda, &lds[(pb) * 32768 + 8192 + so]); \
        GLOAD_LDS16(pa_st + k64_ + (size_t)96 * lda, &lds[(pb) * 32768 + 12288 + so]); \
    } \
} while (0)

    f32x4 acc[8][4] = {};

    SPAIR(0, 0, 0); SPAIR(1, 0, 0); SPAIR(2, 0, 0);
    SFENCE;
    SPAIR(3, 0, 0);

    for (int kt = 0; kt < NT; ++kt) {
        const int p = kt & 1;
        const bool sn = (kt + 1 < NT);
        const u16t* lA = &lds[p * 32768];

        asm volatile("s_waitcnt vmcnt(2)" ::: "memory");
        __builtin_amdgcn_s_barrier();

        bf16x8 bfr[4][2];
#pragma unroll
        for (int ni = 0; ni < 4; ++ni) {
            bfr[ni][0] = *(const bf16x8*)&lA[bbase + ni * 1024 + colk0];
            bfr[ni][1] = *(const bf16x8*)&lA[bbase + ni * 1024 + colk1];
        }
        bf16x8 af1[2][2][2];
#pragma unroll
        for (int g = 0; g < 2; ++g) {
            af1[g][0][0] = *(const bf16x8*)&lA[g * 4096 + abase + colk0];
            af1[g][0][1] = *(const bf16x8*)&lA[g * 4096 + abase + colk1];
            af1[g][1][0] = *(const bf16x8*)&lA[g * 4096 + abase + 1024 + colk0];
            af1[g][1][1] = *(const bf16x8*)&lA[g * 4096 + abase + 1024 + colk1];
        }
        if (sn) { SPAIR(0, kt + 1, p ^ 1); SPAIR(1, kt + 1, p ^ 1); SPAIR(2, kt + 1, p ^ 1); }
        __builtin_amdgcn_s_setprio(1);
#pragma unroll
        for (int g = 0; g < 2; ++g)
#pragma unroll
            for (int dm = 0; dm < 2; ++dm)
#pragma unroll
                for (int ni = 0; ni < 4; ++ni)
#pragma unroll
                    for (int kk = 0; kk < 2; ++kk)
                        acc[g * 2 + dm][ni] = __builtin_amdgcn_mfma_f32_16x16x32_bf16(
                            af1[g][dm][kk], bfr[ni][kk], acc[g * 2 + dm][ni], 0, 0, 0);
        __builtin_amdgcn_s_setprio(0);

        if (sn) asm volatile("s_waitcnt vmcnt(6)" ::: "memory");
        else    asm volatile("s_waitcnt vmcnt(0)" ::: "memory");
        __builtin_amdgcn_s_barrier();

        bf16x8 af2[2][2][2];
#pragma unroll
        for (int g = 0; g < 2; ++g) {
            af2[g][0][0] = *(const bf16x8*)&lA[(g + 2) * 4096 + abase + colk0];
            af2[g][0][1] = *(const bf16x8*)&lA[(g + 2) * 4096 + abase + colk1];
            af2[g][1][0] = *(const bf16x8*)&lA[(g + 2) * 4096 + abase + 1024 + colk0];
            af2[g][1][1] = *(const bf16x8*)&lA[(g + 2) * 4096 + abase + 1024 + colk1];
        }
        if (sn) SPAIR(3, kt + 1, p ^ 1);
        __builtin_amdgcn_s_setprio(1);
#pragma unroll
        for (int g = 0; g < 2; ++g)
#pragma unroll
            for (int dm = 0; dm < 2; ++dm)
#pragma unroll
                for (int ni = 0; ni < 4; ++ni)
#pragma unroll
                    for (int kk = 0; kk < 2; ++kk)
                        acc[4 + g * 2 + dm][ni] = __builtin_amdgcn_mfma_f32_16x16x32_bf16(
                            af2[g][dm][kk], bfr[ni][kk], acc[4 + g * 2 + dm][ni], 0, 0, 0);
        __builtin_amdgcn_s_setprio(0);
    }
#undef SPAIR

    if (KSUM && n0 >= 1024 && n0 < 2048) {
        // ---- fused k-epilogue: store bf16(exp(acc)) + per-column sum(exp) -> ksum ----
        // exp consumed immediately (no extra liveness); one exp per element.
#pragma unroll
        for (int ni = 0; ni < 4; ++ni) {
            int col = n0 + wn * 64 + ni * 16 + (l & 15);
            float se = 0.f;
#pragma unroll
            for (int mi = 0; mi < 8; ++mi) {
                int row = m0 + wm * 128 + mi * 16 + ((l >> 4) << 2);
#pragma unroll
                for (int j = 0; j < 4; ++j) {
                    float e = __expf(acc[mi][ni][j]);
                    se += e;
                    ((u16t*)Cout)[(size_t)(row + j) * N + col] = f2bf(e);
                }
            }
            se += __shfl_xor(se, 16);
            se += __shfl_xor(se, 32);
            if ((l >> 4) == 0)
                atomicAdd(&ksum[(by >> 4) * 1024 + (n0 - 1024) + wn * 64 + ni * 16 + l], se);
        }
    } else {
        // ---- generic epilogue ----
#pragma unroll
        for (int mi = 0; mi < 8; ++mi) {
            int row = m0 + wm * 128 + mi * 16 + ((l >> 4) << 2);
#pragma unroll
            for (int ni = 0; ni < 4; ++ni) {
                int col = n0 + wn * 64 + ni * 16 + (l & 15);
                float bv = BIAS ? bias[col] : 0.f;
#pragma unroll
                for (int j = 0; j < 4; ++j) {
                    float v = acc[mi][ni][j] + bv;
                    if (OUTF32) ((float*)Cout)[(size_t)(row + j) * N + col] = v;
                    else        ((u16t*)Cout)[(size_t)(row + j) * N + col] = f2bf(v);
                }
            }
        }
    }
}

// GEMM1: [16384,1024] x [1024,3072] -> qkv bf16 (k third stored as exp(k)), + k col sums
__global__ __launch_bounds__(512, 2) void gemm_qkv(const u16t* __restrict__ A, const u16t* __restrict__ Bt,
                                                   u16t* __restrict__ C, float* __restrict__ ksum) {
    gemm256_body<0, 0, 0, 1>(A, Bt, C, nullptr, ksum, 16384, 3072, 1024, 12, 1024);
}

// final: out[b] = qsm[b] (lda=3072, cols 0..1023) x W2T[b]^T + bias, f32
__global__ __launch_bounds__(512, 2) void gemm_out(const u16t* __restrict__ A, const u16t* __restrict__ Bt,
                                                   float* __restrict__ C, const float* __restrict__ bias) {
    gemm256_body<1, 1, 1, 0>(A, Bt, C, bias, nullptr, 16384, 1024, 1024, 4, 3072);
}

// ---------------- post_qkv: context (blocks 0..511) ++ q_softmax (512..1535) ----------
// ctx: ctxT[bh][e][d] = (sum_n v[n][e]*ek[n][d]) / ksum[d], where ek = stored exp(k).
// LDS XOR-swizzled transpose staging (ushort8 loads, direct u16 copies - no VALU cvt).
// qsm: in-place softmax over d=64 per row-head, * SCALE, 8-lane groups.
__global__ __launch_bounds__(256) void post_qkv(u16t* __restrict__ qkv,
                                                const float* __restrict__ ksum,
                                                float* __restrict__ ctxT) {
    int bid = blockIdx.x, t = threadIdx.x;
    if (bid < 512) {
        int bh = bid >> 3, chunk = bid & 7;
        int b = bh >> 4, h = bh & 15;
        __shared__ u16t kT[64 * 136];
        __shared__ u16t vT[64 * 136];
        int lane = t & 63, w = t >> 6;
        f32x4 acc[4] = {};
        for (int sub = 0; sub < 4; sub++) {
            size_t rowbase = ((size_t)b * 4096 + chunk * 512 + sub * 128) * 3072 + h * 64;
#pragma unroll
            for (int i = 0; i < 4; i++) {
                int P = t + 256 * i;          // (n, d-chunk) pair
                int n = P >> 3, c = P & 7;
                size_t ro = rowbase + (size_t)n * 3072 + c * 8;
                ushort8 k8 = *(const ushort8*)(&qkv[ro + 1024]);   // already exp(k) bf16
                ushort8 v8 = *(const ushort8*)(&qkv[ro + 2048]);
                int nx = n ^ (c << 3);
#pragma unroll
                for (int j = 0; j < 8; j++) {
                    kT[(c * 8 + j) * 136 + nx] = k8[j];
                    vT[(c * 8 + j) * 136 + nx] = v8[j];
                }
            }
            __syncthreads();
#pragma unroll
            for (int ks = 0; ks < 4; ks++) {
                int er = w * 16 + (lane & 15);
                int nb = ks * 32 + ((lane >> 4) << 3);
                bf16x8 a = *(const bf16x8*)(&vT[er * 136 + (nb ^ ((er >> 3) << 3))]);
#pragma unroll
                for (int ct = 0; ct < 4; ct++) {
                    int dr = ct * 16 + (lane & 15);
                    bf16x8 bb = *(const bf16x8*)(&kT[dr * 136 + (nb ^ ((dr >> 3) << 3))]);
                    acc[ct] = __builtin_amdgcn_mfma_f32_16x16x32_bf16(a, bb, acc[ct], 0, 0, 0);
                }
            }
            __syncthreads();
        }
#pragma unroll
        for (int ct = 0; ct < 4; ct++) {
            int e = w * 16 + ((lane >> 4) << 2);
            int dd = ct * 16 + (lane & 15);
            float gi = 1.0f / ksum[b * 1024 + h * 64 + dd];
#pragma unroll
            for (int j = 0; j < 4; j++)
                atomicAdd(&ctxT[(size_t)bh * 4096 + (e + j) * 64 + dd], acc[ct][j] * gi);
        }
        return;
    }
    // ---- q softmax rows ----
    int qb = bid - 512;
#pragma unroll
    for (int it = 0; it < 8; ++it) {
        int r = qb * 256 + it * 32 + (t >> 3);
        size_t addr = (size_t)(r >> 4) * 3072 + (r & 15) * 64 + (t & 7) * 8;
        ushort8 ch = *(const ushort8*)(&qkv[addr]);
        float v0 = bf2f(ch[0]), v1 = bf2f(ch[1]), v2 = bf2f(ch[2]), v3 = bf2f(ch[3]);
        float v4 = bf2f(ch[4]), v5 = bf2f(ch[5]), v6 = bf2f(ch[6]), v7 = bf2f(ch[7]);
        float m = fmaxf(fmaxf(fmaxf(v0, v1), fmaxf(v2, v3)), fmaxf(fmaxf(v4, v5), fmaxf(v6, v7)));
        m = fmaxf(m, __shfl_xor(m, 1)); m = fmaxf(m, __shfl_xor(m, 2)); m = fmaxf(m, __shfl_xor(m, 4));
        float e0 = __expf(v0 - m), e1 = __expf(v1 - m), e2 = __expf(v2 - m), e3 = __expf(v3 - m);
        float e4 = __expf(v4 - m), e5 = __expf(v5 - m), e6 = __expf(v6 - m), e7 = __expf(v7 - m);
        float s = e0 + e1 + e2 + e3 + e4 + e5 + e6 + e7;
        s += __shfl_xor(s, 1); s += __shfl_xor(s, 2); s += __shfl_xor(s, 4);
        float inv = 0.125f / s;
        ushort8 o;
        o[0] = f2bf(e0 * inv); o[1] = f2bf(e1 * inv); o[2] = f2bf(e2 * inv); o[3] = f2bf(e3 * inv);
        o[4] = f2bf(e4 * inv); o[5] = f2bf(e5 * inv); o[6] = f2bf(e6 * inv); o[7] = f2bf(e7 * inv);
        *(ushort8*)(&qkv[addr]) = o;
    }
}

// ---------------- W2: W2T[b][j][h*64+d] = sum_e ctxT[bh][e][d] * woutT[j][h*64+e] ----
__global__ __launch_bounds__(256) void w2_kernel(const float* __restrict__ ctxT,
                                                 const u16t* __restrict__ woutT,
                                                 u16t* __restrict__ w2t) {
    int bh = blockIdx.x, jc = blockIdx.y;
    int b = bh >> 4, h = bh & 15;
    __shared__ u16t cb[64][72];
    __shared__ u16t wl[256][72];
    int t = threadIdx.x;
#pragma unroll
    for (int i = 0; i < 16; i++) {
        int f = t + 256 * i;
        cb[f & 63][f >> 6] = f2bf(ctxT[(size_t)bh * 4096 + f]);
    }
#pragma unroll
    for (int i = 0; i < 8; i++) {
        int f = t + 256 * i;
        int r = f >> 3, q = f & 7;
        *(uint4*)(&wl[r][q * 8]) = *(const uint4*)(&woutT[(size_t)(jc * 256 + r) * 1024 + h * 64 + q * 8]);
    }
    __syncthreads();
    int l = t & 63, w = t >> 6;
    f32x4 acc[4][4] = {};
#pragma unroll
    for (int kk = 0; kk < 2; kk++) {
        bf16x8 af[4], bfr[4];
#pragma unroll
        for (int mt = 0; mt < 4; mt++)
            af[mt] = *(const bf16x8*)&wl[w * 64 + mt * 16 + (l & 15)][(l >> 4) * 8 + kk * 32];
#pragma unroll
        for (int nt = 0; nt < 4; nt++)
            bfr[nt] = *(const bf16x8*)&cb[nt * 16 + (l & 15)][(l >> 4) * 8 + kk * 32];
#pragma unroll
        for (int mt = 0; mt < 4; mt++)
#pragma unroll
            for (int nt = 0; nt < 4; nt++)
                acc[mt][nt] = __builtin_amdgcn_mfma_f32_16x16x32_bf16(af[mt], bfr[nt], acc[mt][nt], 0, 0, 0);
    }
#pragma unroll
    for (int mt = 0; mt < 4; mt++) {
        int j = jc * 256 + w * 64 + mt * 16 + ((l >> 4) << 2);
#pragma unroll
        for (int nt = 0; nt < 4; nt++) {
            int dd = nt * 16 + (l & 15);
#pragma unroll
            for (int jj = 0; jj < 4; jj++)
                w2t[((size_t)b << 20) + (size_t)(j + jj) * 1024 + h * 64 + dd] = f2bf(acc[mt][nt][jj]);
        }
    }
}

// ---------------- launch ----------------

extern "C" void kernel_launch(void* const* d_in, const int* in_sizes, int n_in,
                              void* d_out, int out_size, void* d_ws, size_t ws_size,
                              hipStream_t stream) {
    const float* x     = (const float*)d_in[0];
    const float* w_qkv = (const float*)d_in[1];
    const float* w_out = (const float*)d_in[2];
    const float* b_out = (const float*)d_in[3];
    float* out = (float*)d_out;
    char* ws = (char*)d_ws;

    size_t o_xb    = 0;                       // 16384*1024*2 = 33554432 (reused as w2t)
    size_t o_wqkvT = 33554432;                // 3072*1024*2  = 6291456
    size_t o_woutT = 39845888;                // 1024*1024*2  = 2097152
    size_t o_qkv   = 41943040;                // 16384*3072*2 = 100663296
    size_t o_ctx   = 142606336;               // 64*64*64*4   = 1048576
    size_t o_ksum  = 143654912;               // 65536 (contiguous after ctx for zeroing)
    size_t needed  = 143720448;
    if (ws_size < needed) return;

    u16t* xb     = (u16t*)(ws + o_xb);
    u16t* w2t    = (u16t*)(ws + o_xb);        // reuse (xb dead after gemm_qkv)
    u16t* wqkvT  = (u16t*)(ws + o_wqkvT);
    u16t* woutT  = (u16t*)(ws + o_woutT);
    u16t* qkvb   = (u16t*)(ws + o_qkv);
    float* ctxT  = (float*)(ws + o_ctx);
    float* ksum  = (float*)(ws + o_ksum);

    // cvt + both weight transposes + zero(ctxT,ksum), one launch
    prep_kernel<<<6212, 256, 0, stream>>>(x, xb, w_qkv, wqkvT, w_out, woutT, ctxT);

    // GEMM1: [16384,1024] x [1024,3072] -> qkv (k third = exp(k)), k col sums -> ksum
    gemm_qkv<<<768, 512, 0, stream>>>(xb, wqkvT, qkvb, ksum);

    // context (512 blocks) ++ q softmax (1024 blocks), one launch
    post_qkv<<<1536, 256, 0, stream>>>(qkvb, ksum, ctxT);

    // W2T[b][j][hd] = sum_e ctx[bh][e][d] * w_out[he][j]
    w2_kernel<<<dim3(64, 4), 256, 0, stream>>>(ctxT, woutT, w2t);

    // out[b] = qsm[b] x W2T[b]^T + bias (f32)
    gemm_out<<<256, 512, 0, stream>>>(qkvb, w2t, out, b_out);
}

// Round 16
// 172.900 us; speedup vs baseline: 2.2324x; 1.1208x over previous
//
#include <hip/hip_runtime.h>
#include <hip/hip_bf16.h>

// LinearAttention (efficient attention): B=4 N=4096 D_MODEL=1024 H=16 DH=64
// Pipeline (5 launches):
//   prep(cvt + 2 transposes + zero ctx/ksum) -> gemm_qkv (256^2 barrier-lite;
//   kv blocks fuse CONTEXT in epilogue: ek=exp(k-acc), ctx_partial = v^T ek via
//   LDS-restaged MFMA, atomicAdd -> ctxT unnormalized + ksum partials; k/v never
//   written to HBM) -> w2 (normalizes ctx by 1/ksum at staging) -> q_softmax ->
//   gemm_out.  attn_gemm eliminated via (qsm*ctx)*w_out == qsm*(ctx*w_out).
//   k-softmax max-pass eliminated (|k| <= ~6 -> exp f32-safe).

typedef unsigned short u16t;
typedef __bf16 bf16x8 __attribute__((ext_vector_type(8)));
typedef float f32x4 __attribute__((ext_vector_type(4)));
typedef unsigned short ushort8 __attribute__((ext_vector_type(8)));
typedef unsigned short u16x4 __attribute__((ext_vector_type(4)));

__device__ __forceinline__ u16t f2bf(float f) {
    union { float f; unsigned int u; } v; v.f = f;
    unsigned int r = v.u + 0x7fffu + ((v.u >> 16) & 1u);
    return (u16t)(r >> 16);
}
__device__ __forceinline__ float bf2f(u16t h) {
    union { unsigned int u; float f; } v; v.u = ((unsigned int)h) << 16;
    return v.f;
}

#define GLOAD_LDS16(gptr, lptr) \
    __builtin_amdgcn_global_load_lds((const __attribute__((address_space(1))) unsigned int*)(gptr), \
                                     (__attribute__((address_space(3))) unsigned int*)(lptr), 16, 0, 0)
#define SFENCE asm volatile("" ::: "memory")

// ---------------- prep: cvt x->bf16 (0..2047) | transpose wqkv (2048..5119)
//                  | transpose wout (5120..6143) | zero ctxT+ksum (6144..6211) --------
__global__ __launch_bounds__(256) void prep_kernel(const float* __restrict__ x, u16t* __restrict__ xb,
                                                   const float* __restrict__ w_qkv, u16t* __restrict__ wqkvT,
                                                   const float* __restrict__ w_out, u16t* __restrict__ woutT,
                                                   float* __restrict__ zbase) {
    int bid = blockIdx.x, t = threadIdx.x;
    if (bid < 2048) {
        int i = (bid * 256 + t) * 4;
        for (; i < 16777216; i += 2048 * 256 * 4) {
            float4 v = *(const float4*)(x + i);
            ushort4 o;
            o.x = f2bf(v.x); o.y = f2bf(v.y); o.z = f2bf(v.z); o.w = f2bf(v.w);
            *(ushort4*)(xb + i) = o;
        }
        return;
    }
    if (bid >= 6144) {
        float4* z = (float4*)zbase;
        int i = (bid - 6144) * 256 + t;
        for (; i < 69632; i += 68 * 256) z[i] = make_float4(0.f, 0.f, 0.f, 0.f);
        return;
    }
    __shared__ float tile[32][33];
    const float* in; u16t* out; int R, C, bx, by;
    if (bid < 5120) { in = w_qkv; out = wqkvT; R = 1024; C = 3072; int b2 = bid - 2048; bx = b2 % 96; by = b2 / 96; }
    else            { in = w_out; out = woutT; R = 1024; C = 1024; int b3 = bid - 5120; bx = b3 & 31; by = b3 >> 5; }
    int c0 = bx * 32, r0 = by * 32;
    int tx = t & 31, ty = t >> 5;
    for (int i = 0; i < 32; i += 8)
        tile[ty + i][tx] = in[(size_t)(r0 + ty + i) * C + c0 + tx];
    __syncthreads();
    for (int i = 0; i < 32; i += 8)
        out[(size_t)(c0 + ty + i) * R + r0 + tx] = f2bf(tile[tx][ty + i]);
}

// ---------------- 256x256 barrier-lite bf16 GEMM body: C = A * Bt^T ----------------
// A [M][lda] bf16 row-major, Bt [N][K] bf16 row-major. 512 threads = 8 waves (2Mx4N),
// per-wave 128x64, BK=64, LDS 128KB dbuf, T2 swizzle (conflict-free), XCD-bijective
// grid swizzle, 2 barriers/K-tile, counted vmcnt.
// KV=1 (gemm_qkv): bx<4 = q blocks (write q cols, N-stride); bx>=4 = kv-fused blocks:
//   B panel rows = {k: 1024+hp*128..+127} U {v: 2048+hp*128..+127}, hp=bx-4.
//   Epilogue: ek=exp(acc[k]), write ekT/vT to LDS (granule-XOR swizzle), ksum partials,
//   then 2-head 64x64x256 product -> atomicAdd ctxT (unnormalized). No HBM k/v.
template<int OUTF32, int BIAS, int BATCHB, int KV>
__device__ __forceinline__ void gemm256_body(const u16t* __restrict__ A, const u16t* __restrict__ Bt,
                                             void* __restrict__ Cout, const float* __restrict__ bias,
                                             float* __restrict__ ksum, float* __restrict__ ctxT,
                                             int M, int N, int K, int NBX, int lda) {
    __shared__ __align__(16) u16t lds[65536];   // 128 KB
    const int t = threadIdx.x;
    const int l = t & 63, w = t >> 6;
    const int wm = w >> 2, wn = w & 3;

    int cpx = gridDim.x >> 3;
    int wg = ((int)blockIdx.x & 7) * cpx + ((int)blockIdx.x >> 3);
    int bx = wg % NBX, by = wg / NBX;
    const int m0 = by * 256, n0 = bx * 256;
    const int NT = K >> 6;
    if (BATCHB) Bt += (size_t)(by >> 4) << 20;

    const int colk0 = ((l >> 4) ^ (l & 7)) * 8;
    const int colk1 = colk0 ^ 32;
    const int abase = (wm * 32 + (l & 15)) * 64;
    const int bbase = 16384 + (wn >> 1) * 8192 + ((wn & 1) * 64 + (l & 15)) * 64;

    const int rr = w * 8 + (l >> 3);
    const int coloff = ((l ^ (l >> 3)) & 7) * 8;
    const int rowA = rr + ((rr >= 32) ? 96 : 0);
    const u16t* pa_st = A + (size_t)(m0 + rowA) * lda + coloff;
    int rb0, rb1;
    if (KV && bx >= 4) { int hp = bx - 4; rb0 = 1024 + hp * 128; rb1 = 2048 + hp * 128; }
    else               { rb0 = n0; rb1 = n0 + 128; }
    const u16t* pb0 = Bt + (size_t)(rb0 + rr) * K + coloff;
    const u16t* pb1 = Bt + (size_t)(rb1 + rr) * K + coloff;
    const int so = w * 512;

#define SPAIR(qq, kto, pb) do { \
    size_t k64_ = (size_t)(kto) * 64; \
    if ((qq) == 0) { \
        GLOAD_LDS16(pb0 + k64_,                  &lds[(pb) * 32768 + 16384 + so]); \
        GLOAD_LDS16(pb0 + k64_ + (size_t)64 * K, &lds[(pb) * 32768 + 20480 + so]); \
    } else if ((qq) == 1) { \
        GLOAD_LDS16(pb1 + k64_,                  &lds[(pb) * 32768 + 24576 + so]); \
        GLOAD_LDS16(pb1 + k64_ + (size_t)64 * K, &lds[(pb) * 32768 + 28672 + so]); \
    } else if ((qq) == 2) { \
        GLOAD_LDS16(pa_st + k64_,                    &lds[(pb) * 32768 + so]); \
        GLOAD_LDS16(pa_st + k64_ + (size_t)32 * lda, &lds[(pb) * 32768 + 4096 + so]); \
    } else { \
        GLOAD_LDS16(pa_st + k64_ + (size_t)64 * lda, &lds[(pb) * 32768 + 8192 + so]); \
        GLOAD_LDS16(pa_st + k64_ + (size_t)96 * lda, &lds[(pb) * 32768 + 12288 + so]); \
    } \
} while (0)

    f32x4 acc[8][4] = {};

    SPAIR(0, 0, 0); SPAIR(1, 0, 0); SPAIR(2, 0, 0);
    SFENCE;
    SPAIR(3, 0, 0);

    for (int kt = 0; kt < NT; ++kt) {
        const int p = kt & 1;
        const bool sn = (kt + 1 < NT);
        const u16t* lA = &lds[p * 32768];

        asm volatile("s_waitcnt vmcnt(2)" ::: "memory");
        __builtin_amdgcn_s_barrier();

        bf16x8 bfr[4][2];
#pragma unroll
        for (int ni = 0; ni < 4; ++ni) {
            bfr[ni][0] = *(const bf16x8*)&lA[bbase + ni * 1024 + colk0];
            bfr[ni][1] = *(const bf16x8*)&lA[bbase + ni * 1024 + colk1];
        }
        bf16x8 af1[2][2][2];
#pragma unroll
        for (int g = 0; g < 2; ++g) {
            af1[g][0][0] = *(const bf16x8*)&lA[g * 4096 + abase + colk0];
            af1[g][0][1] = *(const bf16x8*)&lA[g * 4096 + abase + colk1];
            af1[g][1][0] = *(const bf16x8*)&lA[g * 4096 + abase + 1024 + colk0];
            af1[g][1][1] = *(const bf16x8*)&lA[g * 4096 + abase + 1024 + colk1];
        }
        if (sn) { SPAIR(0, kt + 1, p ^ 1); SPAIR(1, kt + 1, p ^ 1); SPAIR(2, kt + 1, p ^ 1); }
        __builtin_amdgcn_s_setprio(1);
#pragma unroll
        for (int g = 0; g < 2; ++g)
#pragma unroll
            for (int dm = 0; dm < 2; ++dm)
#pragma unroll
                for (int ni = 0; ni < 4; ++ni)
#pragma unroll
                    for (int kk = 0; kk < 2; ++kk)
                        acc[g * 2 + dm][ni] = __builtin_amdgcn_mfma_f32_16x16x32_bf16(
                            af1[g][dm][kk], bfr[ni][kk], acc[g * 2 + dm][ni], 0, 0, 0);
        __builtin_amdgcn_s_setprio(0);

        if (sn) asm volatile("s_waitcnt vmcnt(6)" ::: "memory");
        else    asm volatile("s_waitcnt vmcnt(0)" ::: "memory");
        __builtin_amdgcn_s_barrier();

        bf16x8 af2[2][2][2];
#pragma unroll
        for (int g = 0; g < 2; ++g) {
            af2[g][0][0] = *(const bf16x8*)&lA[(g + 2) * 4096 + abase + colk0];
            af2[g][0][1] = *(const bf16x8*)&lA[(g + 2) * 4096 + abase + colk1];
            af2[g][1][0] = *(const bf16x8*)&lA[(g + 2) * 4096 + abase + 1024 + colk0];
            af2[g][1][1] = *(const bf16x8*)&lA[(g + 2) * 4096 + abase + 1024 + colk1];
        }
        if (sn) SPAIR(3, kt + 1, p ^ 1);
        __builtin_amdgcn_s_setprio(1);
#pragma unroll
        for (int g = 0; g < 2; ++g)
#pragma unroll
            for (int dm = 0; dm < 2; ++dm)
#pragma unroll
                for (int ni = 0; ni < 4; ++ni)
#pragma unroll
                    for (int kk = 0; kk < 2; ++kk)
                        acc[4 + g * 2 + dm][ni] = __builtin_amdgcn_mfma_f32_16x16x32_bf16(
                            af2[g][dm][kk], bfr[ni][kk], acc[4 + g * 2 + dm][ni], 0, 0, 0);
        __builtin_amdgcn_s_setprio(0);
    }
#undef SPAIR

    if (KV && bx >= 4) {
        // ---- fused context epilogue (2 heads) ----
        const int hp = bx - 4;
        const int bb = by >> 4;
        __syncthreads();                       // protect other waves' last-tile ds_reads
        u16t* ekT = lds;                       // [128 d'][256 r], granule-XOR swizzled
        u16t* vT  = lds + 32768;               // [128 e'][256 r]
#define EADDR(dp, r) ((dp) * 256 + ((r) ^ (((dp) & 15) << 2)))
        if (wn < 2) {
#pragma unroll
            for (int ni = 0; ni < 4; ++ni) {
                int dp = wn * 64 + ni * 16 + (l & 15);
                float se = 0.f;
#pragma unroll
                for (int mi = 0; mi < 8; ++mi) {
                    int r0 = wm * 128 + mi * 16 + ((l >> 4) << 2);
                    u16x4 pk;
#pragma unroll
                    for (int j = 0; j < 4; ++j) { float e = __expf(acc[mi][ni][j]); se += e; pk[j] = f2bf(e); }
                    *(u16x4*)&ekT[EADDR(dp, r0)] = pk;
                }
                se += __shfl_xor(se, 16);
                se += __shfl_xor(se, 32);
                if ((l >> 4) == 0)
                    atomicAdd(&ksum[bb * 1024 + hp * 128 + dp], se);
            }
        } else {
#pragma unroll
            for (int ni = 0; ni < 4; ++ni) {
                int ep = (wn - 2) * 64 + ni * 16 + (l & 15);
#pragma unroll
                for (int mi = 0; mi < 8; ++mi) {
                    int r0 = wm * 128 + mi * 16 + ((l >> 4) << 2);
                    u16x4 pv;
#pragma unroll
                    for (int j = 0; j < 4; ++j) pv[j] = f2bf(acc[mi][ni][j]);
                    *(u16x4*)&vT[EADDR(ep, r0)] = pv;
                }
            }
        }
        __syncthreads();
        // head-product: wave w -> head = w>>2, tn = w&3; tiles tm 0..3; K = 256 rows
        const int head = w >> 2, tn = w & 3;
        const int dp2 = head * 64 + tn * 16 + (l & 15);
        const int sb2 = (dp2 & 15) << 2;
        f32x4 acc2[4] = {};
#pragma unroll
        for (int ks = 0; ks < 8; ++ks) {
            int rk = ks * 32 + ((l >> 4) << 3);
            union { u16x4 h[2]; bf16x8 v; } bu;
            bu.h[0] = *(const u16x4*)&ekT[dp2 * 256 + (rk ^ sb2)];
            bu.h[1] = *(const u16x4*)&ekT[dp2 * 256 + ((rk + 4) ^ sb2)];
#pragma unroll
            for (int tm = 0; tm < 4; ++tm) {
                int ep = head * 64 + tm * 16 + (l & 15);
                int sa = (ep & 15) << 2;
                union { u16x4 h[2]; bf16x8 v; } au;
                au.h[0] = *(const u16x4*)&vT[ep * 256 + (rk ^ sa)];
                au.h[1] = *(const u16x4*)&vT[ep * 256 + ((rk + 4) ^ sa)];
                acc2[tm] = __builtin_amdgcn_mfma_f32_16x16x32_bf16(au.v, bu.v, acc2[tm], 0, 0, 0);
            }
        }
#undef EADDR
        int bh = bb * 16 + hp * 2 + head;
#pragma unroll
        for (int tm = 0; tm < 4; ++tm) {
            int e = tm * 16 + ((l >> 4) << 2);
            int dd = tn * 16 + (l & 15);
#pragma unroll
            for (int j = 0; j < 4; ++j)
                atomicAdd(&ctxT[(size_t)bh * 4096 + (e + j) * 64 + dd], acc2[tm][j]);
        }
    } else {
        // ---- generic epilogue ----
#pragma unroll
        for (int mi = 0; mi < 8; ++mi) {
            int row = m0 + wm * 128 + mi * 16 + ((l >> 4) << 2);
#pragma unroll
            for (int ni = 0; ni < 4; ++ni) {
                int col = n0 + wn * 64 + ni * 16 + (l & 15);
                float bv = BIAS ? bias[col] : 0.f;
#pragma unroll
                for (int j = 0; j < 4; ++j) {
                    float v = acc[mi][ni][j] + bv;
                    if (OUTF32) ((float*)Cout)[(size_t)(row + j) * N + col] = v;
                    else        ((u16t*)Cout)[(size_t)(row + j) * N + col] = f2bf(v);
                }
            }
        }
    }
}

// GEMM1: [16384,1024] x [1024,3072]; q cols -> qkv; kv blocks -> ctxT/ksum directly
__global__ __launch_bounds__(512, 2) void gemm_qkv(const u16t* __restrict__ A, const u16t* __restrict__ Bt,
                                                   u16t* __restrict__ C, float* __restrict__ ksum,
                                                   float* __restrict__ ctxT) {
    gemm256_body<0, 0, 0, 1>(A, Bt, C, nullptr, ksum, ctxT, 16384, 3072, 1024, 12, 1024);
}

// final: out[b] = qsm[b] (lda=3072, cols 0..1023) x W2T[b]^T + bias, f32
__global__ __launch_bounds__(512, 2) void gemm_out(const u16t* __restrict__ A, const u16t* __restrict__ Bt,
                                                   float* __restrict__ C, const float* __restrict__ bias) {
    gemm256_body<1, 1, 1, 0>(A, Bt, C, bias, nullptr, nullptr, 16384, 1024, 1024, 4, 3072);
}

// ---------------- q softmax (in-place over d=64, * SCALE) ----------------
// grid 1024, block 256; 8-lane groups, ushort8.
__global__ __launch_bounds__(256) void q_softmax_rows(u16t* __restrict__ qkv) {
    int t = threadIdx.x;
#pragma unroll
    for (int it = 0; it < 8; ++it) {
        int r = blockIdx.x * 256 + it * 32 + (t >> 3);
        size_t addr = (size_t)(r >> 4) * 3072 + (r & 15) * 64 + (t & 7) * 8;
        ushort8 ch = *(const ushort8*)(&qkv[addr]);
        float v0 = bf2f(ch[0]), v1 = bf2f(ch[1]), v2 = bf2f(ch[2]), v3 = bf2f(ch[3]);
        float v4 = bf2f(ch[4]), v5 = bf2f(ch[5]), v6 = bf2f(ch[6]), v7 = bf2f(ch[7]);
        float m = fmaxf(fmaxf(fmaxf(v0, v1), fmaxf(v2, v3)), fmaxf(fmaxf(v4, v5), fmaxf(v6, v7)));
        m = fmaxf(m, __shfl_xor(m, 1)); m = fmaxf(m, __shfl_xor(m, 2)); m = fmaxf(m, __shfl_xor(m, 4));
        float e0 = __expf(v0 - m), e1 = __expf(v1 - m), e2 = __expf(v2 - m), e3 = __expf(v3 - m);
        float e4 = __expf(v4 - m), e5 = __expf(v5 - m), e6 = __expf(v6 - m), e7 = __expf(v7 - m);
        float s = e0 + e1 + e2 + e3 + e4 + e5 + e6 + e7;
        s += __shfl_xor(s, 1); s += __shfl_xor(s, 2); s += __shfl_xor(s, 4);
        float inv = 0.125f / s;
        ushort8 o;
        o[0] = f2bf(e0 * inv); o[1] = f2bf(e1 * inv); o[2] = f2bf(e2 * inv); o[3] = f2bf(e3 * inv);
        o[4] = f2bf(e4 * inv); o[5] = f2bf(e5 * inv); o[6] = f2bf(e6 * inv); o[7] = f2bf(e7 * inv);
        *(ushort8*)(&qkv[addr]) = o;
    }
}

// ---------------- W2: W2T[b][j][h*64+d] = sum_e (ctxT[bh][e][d]/ksum[d]) * woutT[j][h*64+e] ----
__global__ __launch_bounds__(256) void w2_kernel(const float* __restrict__ ctxT,
                                                 const float* __restrict__ ksum,
                                                 const u16t* __restrict__ woutT,
                                                 u16t* __restrict__ w2t) {
    int bh = blockIdx.x, jc = blockIdx.y;
    int b = bh >> 4, h = bh & 15;
    __shared__ u16t cb[64][72];
    __shared__ u16t wl[256][72];
    int t = threadIdx.x;
    float ginv = 1.0f / ksum[b * 1024 + h * 64 + (t & 63)];   // f&63 == t&63 for all i
#pragma unroll
    for (int i = 0; i < 16; i++) {
        int f = t + 256 * i;
        cb[f & 63][f >> 6] = f2bf(ctxT[(size_t)bh * 4096 + f] * ginv);
    }
#pragma unroll
    for (int i = 0; i < 8; i++) {
        int f = t + 256 * i;
        int r = f >> 3, q = f & 7;
        *(uint4*)(&wl[r][q * 8]) = *(const uint4*)(&woutT[(size_t)(jc * 256 + r) * 1024 + h * 64 + q * 8]);
    }
    __syncthreads();
    int l = t & 63, w = t >> 6;
    f32x4 acc[4][4] = {};
#pragma unroll
    for (int kk = 0; kk < 2; kk++) {
        bf16x8 af[4], bfr[4];
#pragma unroll
        for (int mt = 0; mt < 4; mt++)
            af[mt] = *(const bf16x8*)&wl[w * 64 + mt * 16 + (l & 15)][(l >> 4) * 8 + kk * 32];
#pragma unroll
        for (int nt = 0; nt < 4; nt++)
            bfr[nt] = *(const bf16x8*)&cb[nt * 16 + (l & 15)][(l >> 4) * 8 + kk * 32];
#pragma unroll
        for (int mt = 0; mt < 4; mt++)
#pragma unroll
            for (int nt = 0; nt < 4; nt++)
                acc[mt][nt] = __builtin_amdgcn_mfma_f32_16x16x32_bf16(af[mt], bfr[nt], acc[mt][nt], 0, 0, 0);
    }
#pragma unroll
    for (int mt = 0; mt < 4; mt++) {
        int j = jc * 256 + w * 64 + mt * 16 + ((l >> 4) << 2);
#pragma unroll
        for (int nt = 0; nt < 4; nt++) {
            int dd = nt * 16 + (l & 15);
#pragma unroll
            for (int jj = 0; jj < 4; jj++)
                w2t[((size_t)b << 20) + (size_t)(j + jj) * 1024 + h * 64 + dd] = f2bf(acc[mt][nt][jj]);
        }
    }
}

// ---------------- launch ----------------

extern "C" void kernel_launch(void* const* d_in, const int* in_sizes, int n_in,
                              void* d_out, int out_size, void* d_ws, size_t ws_size,
                              hipStream_t stream) {
    const float* x     = (const float*)d_in[0];
    const float* w_qkv = (const float*)d_in[1];
    const float* w_out = (const float*)d_in[2];
    const float* b_out = (const float*)d_in[3];
    float* out = (float*)d_out;
    char* ws = (char*)d_ws;

    size_t o_xb    = 0;                       // 16384*1024*2 = 33554432 (reused as w2t)
    size_t o_wqkvT = 33554432;                // 3072*1024*2  = 6291456
    size_t o_woutT = 39845888;                // 1024*1024*2  = 2097152
    size_t o_qkv   = 41943040;                // 16384*3072*2 (q third used)
    size_t o_ctx   = 142606336;               // 64*64*64*4   = 1048576
    size_t o_ksum  = 143654912;               // 65536 (contiguous after ctx for zeroing)
    size_t needed  = 143720448;
    if (ws_size < needed) return;

    u16t* xb     = (u16t*)(ws + o_xb);
    u16t* w2t    = (u16t*)(ws + o_xb);        // reuse (xb dead after gemm_qkv)
    u16t* wqkvT  = (u16t*)(ws + o_wqkvT);
    u16t* woutT  = (u16t*)(ws + o_woutT);
    u16t* qkvb   = (u16t*)(ws + o_qkv);
    float* ctxT  = (float*)(ws + o_ctx);
    float* ksum  = (float*)(ws + o_ksum);

    // cvt + both weight transposes + zero(ctxT,ksum), one launch
    prep_kernel<<<6212, 256, 0, stream>>>(x, xb, w_qkv, wqkvT, w_out, woutT, ctxT);

    // GEMM1 + fused context: q cols -> qkv; kv blocks -> ctxT (unnorm) + ksum
    gemm_qkv<<<768, 512, 0, stream>>>(xb, wqkvT, qkvb, ksum, ctxT);

    // W2T[b][j][hd] = sum_e (ctx/ksum)[bh][e][d] * w_out[he][j]
    w2_kernel<<<dim3(64, 4), 256, 0, stream>>>(ctxT, ksum, woutT, w2t);

    // q softmax in-place
    q_softmax_rows<<<1024, 256, 0, stream>>>(qkvb);

    // out[b] = qsm[b] x W2T[b]^T + bias (f32)
    gemm_out<<<256, 512, 0, stream>>>(qkvb, w2t, out, b_out);
}